// Round 5
// baseline (519.700 us; speedup 1.0000x reference)
//
#include <hip/hip_runtime.h>

// IntSoftmax (I-BERT) on (1,16,2048,2048) fp32. ONE WAVE PER ROW (2048 cols,
// 32 elems/lane): zero __syncthreads, zero LDS, row reductions are pure
// 6-step shfl_xor. Nontemporal 16B loads/stores (streaming, no reuse).
// Round 5: VGPR squeeze for 8 waves/SIMD — load directly into xi[32]
// (aliased f32x4[8]), pack quantized results pairwise into 16 uint regs,
// __launch_bounds__(256, 8) forces the <=64-VGPR allocation.
//
// Bit-exactness notes (verified rounds 1-4, absmax = 0.0):
//  - __f*_rn intrinsics forbid FMA contraction where numpy rounds twice.
//  - x/sf: when sf is a power of two the division is exact, so multiply by
//    the (exact) reciprocal is bit-identical. Runtime-gated on mantissa bits.
//  - r = t - x0*q: x0,q integers, |x0*q| < 2^24 -> product exact ->
//    fmaf(-x0, q, t) rounds once on an exact intermediate == two-step result.
//  - 2^(30-q) built from the exponent field (q in [0,30] guaranteed by clamp).
//  - (xi*factor)/2^24 == (xi*factor)*2^-24 exactly (power-of-two scaling).
//  - round-clamps to [-32768,32767] are dead: rint(qv) provably in [0,32767].
//  - rq in [0,32767] integer -> (unsigned)rq / (float)(p&0xffff) round-trips
//    exactly through the 16-bit pack.
//  - t/x0 and xreal/act_sf keep __fdiv_rn (reciprocal-mul would flip
//    borderline floor/rint decisions -> 1-LSB = 3.9e-3 > 1.0e-3 threshold).
//  - Row sums are exact integer sums < 2^24 -> reduction order irrelevant.
//  - QuantAct global max is analytic (attained at every row's argmax where
//    x_int == 0 exactly) -> no cross-block reduction needed.

typedef float f32x4 __attribute__((ext_vector_type(4)));

constexpr int COLS    = 2048;
constexpr int THREADS = 256;            // 4 waves/block, 1 row per wave
constexpr int ROWS_PER_BLOCK = 4;
constexpr int EPL = 32;                 // elements per lane

__global__ __launch_bounds__(THREADS, 8)
void IntSoftmax_43774306680979_kernel(const float* __restrict__ x,
                                      const float* __restrict__ sfp,
                                      float* __restrict__ out) {
    const int lane = threadIdx.x & 63;
    const int wave = threadIdx.x >> 6;
    const size_t row = (size_t)blockIdx.x * ROWS_PER_BLOCK + wave;
    const float sf = sfp[0];

    // ---- scalar constants, exact float32 replication of reference ----
    const float x0_int = floorf(__fdiv_rn(-0.6931f, sf));                       // floor(X0/sf)
    const float b_int  = floorf(__fdiv_rn((float)(0.96963238 / 0.35815147), sf));
    const float c_int  = floorf(__fdiv_rn((float)(1.0 / 0.35815147),
                                          __fmul_rn(sf, sf)));
    float exp_sf = __fmul_rn(__fmul_rn(0.35815147f, sf), sf);                   // COEF0*sf*sf
    exp_sf = __fdiv_rn(exp_sf, 1073741824.0f);                                  // / 2^30
    const float clampv = __fmul_rn(30.0f, x0_int);                              // CONST*x0_int
    // analytic global max of x_real: exp_int_max = floor(c_int * 2^30)
    const float x_max  = __fmul_rn(floorf(__fmul_rn(c_int, 1073741824.0f)), exp_sf);
    const float act_sf = __fdiv_rn(x_max, 32767.0f);                            // x_max / (2^15-1)
    const float neg_x0 = -x0_int;

    // power-of-two sf => x/sf exact => reciprocal-multiply bit-identical
    const unsigned sfb = __float_as_uint(sf);
    const bool sf_pow2 = ((sfb & 0x007fffffu) == 0u) && ((sfb & 0x7f800000u) != 0u);
    const float inv_sf = __fdiv_rn(1.0f, sf);    // exact when sf_pow2

    // ---- load row straight into xi[32]: 8 coalesced 16B nontemporal loads ----
    const f32x4* __restrict__ xr =
        reinterpret_cast<const f32x4*>(x + row * COLS);
    float xi[EPL];
    f32x4* xv = reinterpret_cast<f32x4*>(xi);
#pragma unroll
    for (int k = 0; k < 8; ++k)
        xv[k] = __builtin_nontemporal_load(&xr[lane + 64 * k]);

    // x_int = x / sf; row max
    float m = -INFINITY;
    if (sf_pow2) {
#pragma unroll
        for (int i = 0; i < EPL; ++i) {
            xi[i] = __fmul_rn(xi[i], inv_sf);
            m = fmaxf(m, xi[i]);
        }
    } else {
#pragma unroll
        for (int i = 0; i < EPL; ++i) {
            xi[i] = __fdiv_rn(xi[i], sf);
            m = fmaxf(m, xi[i]);
        }
    }
#pragma unroll
    for (int off = 32; off > 0; off >>= 1)
        m = fmaxf(m, __shfl_xor(m, off, 64));
    const float rowmax = m;

    // ---- int_exp + int_polynomial + QuantAct(16); pack results 2x16-bit ----
    unsigned pk[EPL / 2];
    float s = 0.0f;
#pragma unroll
    for (int i = 0; i < EPL; ++i) {
        float t = __fsub_rn(xi[i], rowmax);          // x_int - max
        t = fmaxf(t, clampv);                        // max(x_int, 30*x0_int)
        float q = floorf(__fdiv_rn(t, x0_int));      // 0 <= q <= 30
        float r = fmaf(neg_x0, q, t);                // exact product -> bit-exact
        float z = __fadd_rn(__fmul_rn(__fadd_rn(r, b_int), r), c_int);
        int   qi = (int)q;
        float p = __int_as_float((157 - qi) << 23);  // exact 2^(30-q)
        float ei = fmaxf(floorf(__fmul_rn(z, p)), 0.0f);
        float xreal = __fmul_rn(ei, exp_sf);
        float qv = __fdiv_rn(xreal, act_sf);
        float rq = rintf(qv);                        // np.round: half-to-even
        s = __fadd_rn(s, rq);                        // exact integer sum < 2^24
        unsigned pu = (unsigned)rq;                  // exact, in [0, 32767]
        if (i & 1) pk[i >> 1] |= pu << 16;
        else       pk[i >> 1]  = pu;
    }

    // ---- row sum: pure wave reduction, exact ----
#pragma unroll
    for (int off = 32; off > 0; off >>= 1)
        s = __fadd_rn(s, __shfl_xor(s, off, 64));
    const float factor = floorf(__fdiv_rn(4294967296.0f, s));   // floor(2^32/sum)

    // ---- normalize via bit-shift; out = exp_int * 2^-8 ----
    f32x4* __restrict__ orow = reinterpret_cast<f32x4*>(out + row * COLS);
#pragma unroll
    for (int k = 0; k < 8; ++k) {
        f32x4 o;
#pragma unroll
        for (int j = 0; j < 4; ++j) {
            unsigned pw = pk[2 * k + (j >> 1)];
            float ev = (float)((j & 1) ? (pw >> 16) : (pw & 0xffffu)); // exact
            float t = __fmul_rn(__fmul_rn(ev, factor),
                                5.9604644775390625e-8f);        // *2^-24 exact
            o[j] = __fmul_rn(floorf(t), 0.00390625f);           // * 1/256
        }
        __builtin_nontemporal_store(o, &orow[lane + 64 * k]);
    }
}

extern "C" void kernel_launch(void* const* d_in, const int* in_sizes, int n_in,
                              void* d_out, int out_size, void* d_ws, size_t ws_size,
                              hipStream_t stream) {
    const float* x   = (const float*)d_in[0];
    const float* sfp = (const float*)d_in[1];
    float* out       = (float*)d_out;
    const int rows   = in_sizes[0] / COLS;             // 32768
    const int blocks = rows / ROWS_PER_BLOCK;          // 8192
    IntSoftmax_43774306680979_kernel<<<dim3(blocks), dim3(THREADS), 0, stream>>>(
        x, sfp, out);
}

// Round 6
// 418.850 us; speedup vs baseline: 1.2408x; 1.2408x over previous
//
#include <hip/hip_runtime.h>

// IntSoftmax (I-BERT) on (1,16,2048,2048) fp32. ONE WAVE PER ROW (2048 cols,
// 32 elems/lane): zero __syncthreads, zero LDS, row reductions are pure
// 6-step shfl_xor. Nontemporal 16B loads/stores (streaming, no reuse).
// Round 6: round-5's register diet (direct load into xi[32], 16-bit pairwise
// packing of quantized values) WITHOUT the forced __launch_bounds__ minimum —
// round 5 proved (256,8) makes the allocator clamp to 32 VGPRs and spill the
// row to scratch (+500 MB HBM traffic, 205 us kernel). Natural allocation of
// the dieted kernel should be ~low-60s VGPRs; if <=64 the HW grants
// 8 waves/SIMD on its own (occupancy halves at vgpr=64), no spills.
//
// Bit-exactness notes (verified rounds 1-5, absmax = 0.0):
//  - __f*_rn intrinsics forbid FMA contraction where numpy rounds twice.
//  - x/sf: when sf is a power of two the division is exact, so multiply by
//    the (exact) reciprocal is bit-identical. Runtime-gated on mantissa bits.
//  - r = t - x0*q: x0,q integers, |x0*q| < 2^24 -> product exact ->
//    fmaf(-x0, q, t) rounds once on an exact intermediate == two-step result.
//  - 2^(30-q) built from the exponent field (q in [0,30] guaranteed by clamp).
//  - (xi*factor)/2^24 == (xi*factor)*2^-24 exactly (power-of-two scaling).
//  - round-clamps to [-32768,32767] are dead: rint(qv) provably in [0,32767].
//  - rq in [0,32767] integer -> (unsigned)rq / (float)(p&0xffff) round-trips
//    exactly through the 16-bit pack.
//  - t/x0 and xreal/act_sf keep __fdiv_rn (reciprocal-mul would flip
//    borderline floor/rint decisions -> 1-LSB = 3.9e-3 > 1.0e-3 threshold).
//  - Row sums are exact integer sums < 2^24 -> reduction order irrelevant.
//  - QuantAct global max is analytic (attained at every row's argmax where
//    x_int == 0 exactly) -> no cross-block reduction needed.

typedef float f32x4 __attribute__((ext_vector_type(4)));

constexpr int COLS    = 2048;
constexpr int THREADS = 256;            // 4 waves/block, 1 row per wave
constexpr int ROWS_PER_BLOCK = 4;
constexpr int EPL = 32;                 // elements per lane

__global__ __launch_bounds__(THREADS)
void IntSoftmax_43774306680979_kernel(const float* __restrict__ x,
                                      const float* __restrict__ sfp,
                                      float* __restrict__ out) {
    const int lane = threadIdx.x & 63;
    const int wave = threadIdx.x >> 6;
    const size_t row = (size_t)blockIdx.x * ROWS_PER_BLOCK + wave;
    const float sf = sfp[0];

    // ---- scalar constants, exact float32 replication of reference ----
    const float x0_int = floorf(__fdiv_rn(-0.6931f, sf));                       // floor(X0/sf)
    const float b_int  = floorf(__fdiv_rn((float)(0.96963238 / 0.35815147), sf));
    const float c_int  = floorf(__fdiv_rn((float)(1.0 / 0.35815147),
                                          __fmul_rn(sf, sf)));
    float exp_sf = __fmul_rn(__fmul_rn(0.35815147f, sf), sf);                   // COEF0*sf*sf
    exp_sf = __fdiv_rn(exp_sf, 1073741824.0f);                                  // / 2^30
    const float clampv = __fmul_rn(30.0f, x0_int);                              // CONST*x0_int
    // analytic global max of x_real: exp_int_max = floor(c_int * 2^30)
    const float x_max  = __fmul_rn(floorf(__fmul_rn(c_int, 1073741824.0f)), exp_sf);
    const float act_sf = __fdiv_rn(x_max, 32767.0f);                            // x_max / (2^15-1)
    const float neg_x0 = -x0_int;

    // power-of-two sf => x/sf exact => reciprocal-multiply bit-identical
    const unsigned sfb = __float_as_uint(sf);
    const bool sf_pow2 = ((sfb & 0x007fffffu) == 0u) && ((sfb & 0x7f800000u) != 0u);
    const float inv_sf = __fdiv_rn(1.0f, sf);    // exact when sf_pow2

    // ---- load row straight into xi[32]: 8 coalesced 16B nontemporal loads ----
    const f32x4* __restrict__ xr =
        reinterpret_cast<const f32x4*>(x + row * COLS);
    float xi[EPL];
    f32x4* xv = reinterpret_cast<f32x4*>(xi);
#pragma unroll
    for (int k = 0; k < 8; ++k)
        xv[k] = __builtin_nontemporal_load(&xr[lane + 64 * k]);

    // x_int = x / sf; row max
    float m = -INFINITY;
    if (sf_pow2) {
#pragma unroll
        for (int i = 0; i < EPL; ++i) {
            xi[i] = __fmul_rn(xi[i], inv_sf);
            m = fmaxf(m, xi[i]);
        }
    } else {
#pragma unroll
        for (int i = 0; i < EPL; ++i) {
            xi[i] = __fdiv_rn(xi[i], sf);
            m = fmaxf(m, xi[i]);
        }
    }
#pragma unroll
    for (int off = 32; off > 0; off >>= 1)
        m = fmaxf(m, __shfl_xor(m, off, 64));
    const float rowmax = m;

    // ---- int_exp + int_polynomial + QuantAct(16); pack results 2x16-bit ----
    unsigned pk[EPL / 2];
    float s = 0.0f;
#pragma unroll
    for (int i = 0; i < EPL; ++i) {
        float t = __fsub_rn(xi[i], rowmax);          // x_int - max
        t = fmaxf(t, clampv);                        // max(x_int, 30*x0_int)
        float q = floorf(__fdiv_rn(t, x0_int));      // 0 <= q <= 30
        float r = fmaf(neg_x0, q, t);                // exact product -> bit-exact
        float z = __fadd_rn(__fmul_rn(__fadd_rn(r, b_int), r), c_int);
        int   qi = (int)q;
        float p = __int_as_float((157 - qi) << 23);  // exact 2^(30-q)
        float ei = fmaxf(floorf(__fmul_rn(z, p)), 0.0f);
        float xreal = __fmul_rn(ei, exp_sf);
        float qv = __fdiv_rn(xreal, act_sf);
        float rq = rintf(qv);                        // np.round: half-to-even
        s = __fadd_rn(s, rq);                        // exact integer sum < 2^24
        unsigned pu = (unsigned)rq;                  // exact, in [0, 32767]
        if (i & 1) pk[i >> 1] |= pu << 16;
        else       pk[i >> 1]  = pu;
    }

    // ---- row sum: pure wave reduction, exact ----
#pragma unroll
    for (int off = 32; off > 0; off >>= 1)
        s = __fadd_rn(s, __shfl_xor(s, off, 64));
    const float factor = floorf(__fdiv_rn(4294967296.0f, s));   // floor(2^32/sum)

    // ---- normalize via bit-shift; out = exp_int * 2^-8 ----
    f32x4* __restrict__ orow = reinterpret_cast<f32x4*>(out + row * COLS);
#pragma unroll
    for (int k = 0; k < 8; ++k) {
        f32x4 o;
#pragma unroll
        for (int j = 0; j < 4; ++j) {
            unsigned pw = pk[2 * k + (j >> 1)];
            float ev = (float)((j & 1) ? (pw >> 16) : (pw & 0xffffu)); // exact
            float t = __fmul_rn(__fmul_rn(ev, factor),
                                5.9604644775390625e-8f);        // *2^-24 exact
            o[j] = __fmul_rn(floorf(t), 0.00390625f);           // * 1/256
        }
        __builtin_nontemporal_store(o, &orow[lane + 64 * k]);
    }
}

extern "C" void kernel_launch(void* const* d_in, const int* in_sizes, int n_in,
                              void* d_out, int out_size, void* d_ws, size_t ws_size,
                              hipStream_t stream) {
    const float* x   = (const float*)d_in[0];
    const float* sfp = (const float*)d_in[1];
    float* out       = (float*)d_out;
    const int rows   = in_sizes[0] / COLS;             // 32768
    const int blocks = rows / ROWS_PER_BLOCK;          // 8192
    IntSoftmax_43774306680979_kernel<<<dim3(blocks), dim3(THREADS), 0, stream>>>(
        x, sfp, out);
}